// Round 5
// baseline (110.619 us; speedup 1.0000x reference)
//
#include <hip/hip_runtime.h>

#define IMG 8
#define LH 150
#define LQ 10
#define KITER 10   // 9 scan steps + final conv
#define ROW (IMG * IMG + 2)   // 66 floats per batch row

// ds_bpermute with precomputed BYTE address. Full-wave convergence required.
// Used once per item at the end (sel-lane broadcast).
__device__ __forceinline__ float bperm(int byte_addr, float v) {
    return __builtin_bit_cast(float,
        __builtin_amdgcn_ds_bpermute(byte_addr, __builtin_bit_cast(int, v)));
}

// Force a wave-uniform value into an SGPR (scan-weight pinning).
__device__ __forceinline__ float rfl(float v) {
    return __builtin_bit_cast(float,
        __builtin_amdgcn_readfirstlane(__builtin_bit_cast(int, v)));
}

// Static lane swizzle: new_lane = lane ^ 24 within each 32-lane group
// (BitMode offset = (24<<10)|0x1F = 0x601F). Crosses the 16-lane DPP row
// for the y=3 <-> y=4 vertical taps. Full convergence required.
__device__ __forceinline__ float swz24(float v) {
    return __builtin_bit_cast(float,
        __builtin_amdgcn_ds_swizzle(__builtin_bit_cast(int, v), 0x601F));
}

// DPP lane shift within 16-lane rows, bound_ctrl=1 (out-of-bounds -> 0.0).
// Convention (verified R2-R4): SHR:N = lane i <- i-N, SHL:N = lane i <- i+N.
template <int CTRL>
__device__ __forceinline__ float dppf(float v) {
    return __builtin_bit_cast(float,
        __builtin_amdgcn_update_dpp(0, __builtin_bit_cast(int, v),
                                    CTRL, 0xF, 0xF, true));
}
#define DPP_SHR1 0x111   // lane i <- i-1  (x-1); i%16==0,8 -> 0/garbage, mskL-handled
#define DPP_SHL1 0x101   // lane i <- i+1  (x+1)
#define DPP_SHR8 0x118   // lane i <- i-8  (valid i%16>=8, else 0)
#define DPP_SHL8 0x108   // lane i <- i+8  (valid i%16<8, else 0)

// ---------------------------------------------------------------------------
// Single fused kernel. Round-12 structural change:
//  * 2 items/wave (8192 waves -> 8 waves/SIMD residency; R3/R4's 4-item
//    layout capped at 4/SIMD, leaving ~50% stall on the dependent
//    taps->fma->max chain).
//  * lane = item*32 + h*16 + q*8 + x; register r holds row y = h*4 + 2r + q.
//    Vertical taps are row_shr:8/row_shl:8 DPP sums (exactly one term
//    nonzero per lane); the single 16-row-crossing tap (y=3<->4) is one
//    static ds_swizzle (lane^24) per source register: 2 DS ops/step.
//  * weff folded in: every wave computes ws with the same stride-64
//    partials + xor-butterfly as the old weff kernel (bit-identical),
//    removing a dispatch + graph dependency.
// Per-output arithmetic (tap order, fma chains, max trees) mirrors the
// verified R3/R4 kernel exactly; d-row sums only add literal +0.0 terms.
// ---------------------------------------------------------------------------
__global__ __launch_bounds__(256, 8) void vin_kernel(
    const float* __restrict__ S,
    const float* __restrict__ Wh,
    const float* __restrict__ bh,
    const float* __restrict__ Wr,
    const float* __restrict__ Wq,
    const float* __restrict__ w,
    const float* __restrict__ Wfc,
    float* __restrict__ out,
    int B) {
    const int wave = threadIdx.x >> 6;
    const int lane = threadIdx.x & 63;
    const long b0 = (long)(blockIdx.x * 4 + wave) * 2;   // items b0, b0+1
    if (b0 >= B) return;                                  // wave-uniform

    const int item = lane >> 5;        // 0,1
    const int l32  = lane & 31;
    const int h    = l32 >> 4;         // y half (0: y=0..3, 1: y=4..7)
    const int q    = (l32 >> 3) & 1;   // row parity within half
    const int x    = l32 & 7;

    const float mskL = (x > 0) ? 1.f : 0.f;
    const float mskR = (x < 7) ? 1.f : 0.f;
    const float m3   = (h == 1 && q == 0) ? 1.f : 0.f;  // consumers of y=3 via swz
    const float m4   = (h == 0 && q == 1) ? 1.f : 0.f;  // consumers of y=4 via swz

    // ---- ws: collapsed h/r conv weights (exact; bit-identical to the old
    // weff kernel: same stride-64 per-lane partials, same xor-butterfly).
    float p[10];
    #pragma unroll
    for (int t = 0; t < 10; ++t) p[t] = 0.f;
    for (int c = lane; c < LH; c += 64) {
        const float wr = Wr[c];
        #pragma unroll
        for (int t = 0; t < 9; ++t) p[t] = fmaf(wr, Wh[c * 9 + t], p[t]);
        p[9] = fmaf(wr, bh[c], p[9]);
    }
    #pragma unroll
    for (int t = 0; t < 10; ++t)
        #pragma unroll
        for (int off = 32; off > 0; off >>= 1)
            p[t] += __shfl_xor(p[t], off);   // full wave active

    // ---- per-item state
    const long b = b0 + item;
    const float* Sb = S + b * ROW;
    float v[2];
    v[0] = Sb[(h * 4 + q) * 8 + x];        // y = h4 + q     (r=0)
    v[1] = Sb[(h * 4 + 2 + q) * 8 + x];    // y = h4 + 2 + q (r=1)
    const int s1i = (int)Sb[IMG * IMG];
    const int s2i = (int)Sb[IMG * IMG + 1];
    // lane holding (s1,s2): y=s1 -> h=s1>>2, q=s1&1, reg r=(s1>>1)&1
    const int selAddr = ((item << 5) + ((s1i >> 2) << 4) + ((s1i & 1) << 3) + s2i) << 2;
    const float e0 = (((s1i >> 1) & 1) == 0) ? 1.f : 0.f;
    const float e1 = 1.f - e0;

    // Build the 5 window rows d[j] = grid row (h4+q + j-1), j=0..4, and the
    // x-shifted copies. Output r uses rows d[2r..2r+2].
    auto rows5 = [&](const float vv[2], float d[5]) {
        const float X3 = swz24(vv[1]);   // y=3 -> lanes (h1,q0)
        const float X4 = swz24(vv[0]);   // y=4 -> lanes (h0,q1)
        d[1] = vv[0];
        d[3] = vv[1];
        d[2] = dppf<DPP_SHL8>(vv[0]) + dppf<DPP_SHR8>(vv[1]);
        d[0] = fmaf(X3, m3, dppf<DPP_SHR8>(vv[0]));
        d[4] = fmaf(X4, m4, dppf<DPP_SHL8>(vv[1]));
    };
    auto lcr = [&](const float d[5], float L[5], float R[5]) {
        #pragma unroll
        for (int j = 0; j < 5; ++j) {
            L[j] = mskL * dppf<DPP_SHR1>(d[j]);
            R[j] = mskR * dppf<DPP_SHL1>(d[j]);
        }
    };

    // --- r = conv(X, Weff, pad=1) + beff  (in place: v becomes r)
    {
        float d[5], L[5], R[5];
        rows5(v, d); lcr(d, L, R);
        const float bias = p[9];
        #pragma unroll
        for (int r = 0; r < 2; ++r) {
            float a = bias;
            #pragma unroll
            for (int ky = 0; ky < 3; ++ky) {
                const int j = 2 * r + ky;
                a = fmaf(L[j], p[ky * 3 + 0], a);
                a = fmaf(d[j], p[ky * 3 + 1], a);
                a = fmaf(R[j], p[ky * 3 + 2], a);
            }
            v[r] = a;   // d/L/R already captured old v
        }
    }

    // --- qr[o] = conv(r, Wq, pad=1) — loop-invariant across the scan.
    float qr[LQ][2];
    {
        float d[5], L[5], R[5];
        rows5(v, d); lcr(d, L, R);
        #pragma unroll
        for (int o = 0; o < LQ; ++o)
            #pragma unroll
            for (int r = 0; r < 2; ++r) {
                float a = L[2 * r] * Wq[o * 9 + 0];
                a = fmaf(d[2 * r],     Wq[o * 9 + 1], a);
                a = fmaf(R[2 * r],     Wq[o * 9 + 2], a);
                a = fmaf(L[2 * r + 1], Wq[o * 9 + 3], a);
                a = fmaf(d[2 * r + 1], Wq[o * 9 + 4], a);
                a = fmaf(R[2 * r + 1], Wq[o * 9 + 5], a);
                a = fmaf(L[2 * r + 2], Wq[o * 9 + 6], a);
                a = fmaf(d[2 * r + 2], Wq[o * 9 + 7], a);
                a = fmaf(R[2 * r + 2], Wq[o * 9 + 8], a);
                qr[o][r] = a;
            }
    }

    // Pin the 90 scan weights to SGPRs (one-time; scan body then has only
    // 2 ds_swizzle + VALU).
    float wu[LQ][9];
    #pragma unroll
    for (int o = 0; o < LQ; ++o)
        #pragma unroll
        for (int t = 0; t < 9; ++t)
            wu[o][t] = rfl(w[o * 9 + t]);

    // v = max over channels of qr (same tree shape as verified max10)
    #pragma unroll
    for (int r = 0; r < 2; ++r) {
        const float g0 = fmaxf(fmaxf(qr[0][r], qr[1][r]), qr[2][r]);
        const float g1 = fmaxf(fmaxf(qr[3][r], qr[4][r]), qr[5][r]);
        const float g2 = fmaxf(fmaxf(qr[6][r], qr[7][r]), qr[8][r]);
        v[r] = fmaxf(fmaxf(g0, g1), fmaxf(g2, qr[9][r]));
    }

    // --- 9 scan steps: 2 ds_swizzle + DPP taps + 180 fma + max.
    #pragma unroll 1
    for (int k = 0; k < KITER - 1; ++k) {
        float d[5], L[5], R[5];
        rows5(v, d); lcr(d, L, R);
        float m[2];
        #pragma unroll
        for (int o = 0; o < LQ; ++o)
            #pragma unroll
            for (int r = 0; r < 2; ++r) {
                float a = qr[o][r];
                a = fmaf(L[2 * r],     wu[o][0], a);
                a = fmaf(d[2 * r],     wu[o][1], a);
                a = fmaf(R[2 * r],     wu[o][2], a);
                a = fmaf(L[2 * r + 1], wu[o][3], a);
                a = fmaf(d[2 * r + 1], wu[o][4], a);
                a = fmaf(R[2 * r + 1], wu[o][5], a);
                a = fmaf(L[2 * r + 2], wu[o][6], a);
                a = fmaf(d[2 * r + 2], wu[o][7], a);
                a = fmaf(R[2 * r + 2], wu[o][8], a);
                m[r] = (o == 0) ? a : fmaxf(m[r], a);
            }
        v[0] = m[0]; v[1] = m[1];
    }

    // --- Final conv fused with sel extraction + Wfc dot.
    const int row = l32 & 7;
    float osum = 0.f;
    {
        float d[5], L[5], R[5];
        rows5(v, d); lcr(d, L, R);
        #pragma unroll
        for (int o = 0; o < LQ; ++o) {
            float a0, a1;
            #pragma unroll
            for (int r = 0; r < 2; ++r) {
                float a = qr[o][r];
                a = fmaf(L[2 * r],     wu[o][0], a);
                a = fmaf(d[2 * r],     wu[o][1], a);
                a = fmaf(R[2 * r],     wu[o][2], a);
                a = fmaf(L[2 * r + 1], wu[o][3], a);
                a = fmaf(d[2 * r + 1], wu[o][4], a);
                a = fmaf(R[2 * r + 1], wu[o][5], a);
                a = fmaf(L[2 * r + 2], wu[o][6], a);
                a = fmaf(d[2 * r + 2], wu[o][7], a);
                a = fmaf(R[2 * r + 2], wu[o][8], a);
                if (r == 0) a0 = a; else a1 = a;
            }
            float t = a0 * e0;
            t = fmaf(a1, e1, t);                  // one-hot reg select (exact)
            const float qs = bperm(selAddr, t);   // full convergence
            osum = fmaf(qs, Wfc[row * LQ + o], osum);
        }
    }
    // lanes 0..7 of each 32-lane item group emit that item's 8 logits
    if (l32 < 8) out[b * 8 + row] = osum;
}

extern "C" void kernel_launch(void* const* d_in, const int* in_sizes, int n_in,
                              void* d_out, int out_size, void* d_ws, size_t ws_size,
                              hipStream_t stream) {
    const float* S   = (const float*)d_in[0];
    const float* Wh  = (const float*)d_in[1];
    const float* bh  = (const float*)d_in[2];
    const float* Wr  = (const float*)d_in[3];
    const float* Wq  = (const float*)d_in[4];
    const float* w   = (const float*)d_in[5];
    const float* Wfc = (const float*)d_in[6];
    float* out = (float*)d_out;
    (void)d_ws; (void)ws_size;

    const int B = in_sizes[0] / ROW;

    // Single fused kernel: 4 waves/block, 2 items/wave => 8 items per block.
    const int grid = (B + 7) / 8;
    vin_kernel<<<grid, 256, 0, stream>>>(S, Wh, bh, Wr, Wq, w, Wfc, out, B);
}

// Round 6
// 100.397 us; speedup vs baseline: 1.1018x; 1.1018x over previous
//
#include <hip/hip_runtime.h>

#define IMG 8
#define LH 150
#define LQ 10
#define KITER 10   // 9 scan steps + final conv
#define ROW (IMG * IMG + 2)   // 66 floats per batch row

// ds_bpermute with precomputed BYTE address. Full-wave convergence required.
// Used once per item at the end (sel-lane broadcast).
__device__ __forceinline__ float bperm(int byte_addr, float v) {
    return __builtin_bit_cast(float,
        __builtin_amdgcn_ds_bpermute(byte_addr, __builtin_bit_cast(int, v)));
}

// Force a wave-uniform value into an SGPR (scan-weight pinning).
__device__ __forceinline__ float rfl(float v) {
    return __builtin_bit_cast(float,
        __builtin_amdgcn_readfirstlane(__builtin_bit_cast(int, v)));
}

// Static lane swizzle: new_lane = lane ^ 24 within each 32-lane group
// (BitMode offset = (24<<10)|0x1F = 0x601F). Crosses the 16-lane DPP row
// for the y=3 <-> y=4 vertical taps. Full convergence required.
__device__ __forceinline__ float swz24(float v) {
    return __builtin_bit_cast(float,
        __builtin_amdgcn_ds_swizzle(__builtin_bit_cast(int, v), 0x601F));
}

// DPP lane shift within 16-lane rows, bound_ctrl=1 (out-of-bounds -> 0.0).
template <int CTRL>
__device__ __forceinline__ float dppf(float v) {
    return __builtin_bit_cast(float,
        __builtin_amdgcn_update_dpp(0, __builtin_bit_cast(int, v),
                                    CTRL, 0xF, 0xF, true));
}
#define DPP_SHR1 0x111   // lane i <- i-1  (x-1)
#define DPP_SHL1 0x101   // lane i <- i+1  (x+1)
#define DPP_SHR8 0x118   // lane i <- i-8  (valid i%16>=8, else 0)
#define DPP_SHL8 0x108   // lane i <- i+8  (valid i%16<8, else 0)

// ---------------------------------------------------------------------------
// Pre-kernel: collapse h/r convs (exact — no nonlinearity between h and r).
// Back to its own dispatch: R5's per-wave fused version cost ~2000 cyc/wave
// (serial butterfly + loads) x 8192 waves — a 9 us regression.
// ---------------------------------------------------------------------------
__global__ void weff_kernel(const float* __restrict__ Wh,
                            const float* __restrict__ bh,
                            const float* __restrict__ Wr,
                            float* __restrict__ ws) {
    const int wv = threadIdx.x >> 6;   // 0..9 (wave-uniform)
    const int lane = threadIdx.x & 63;
    float partial = 0.f;
    for (int c = lane; c < LH; c += 64) {
        const float wr = Wr[c];
        partial += wr * ((wv < 9) ? Wh[c * 9 + wv] : bh[c]);
    }
    #pragma unroll
    for (int off = 32; off > 0; off >>= 1)
        partial += __shfl_xor(partial, off);   // full wave active
    if (lane == 0) ws[wv] = partial;
}

// ---------------------------------------------------------------------------
// Main kernel. Round-13 = R5's verified 2-item/32-lane layout with the two
// R5 mistakes reverted:
//  (a) weff un-fused (see above);
//  (b) launch_bounds(256,6): 84-VGPR budget. R5's (256,8) 64-cap produced
//      VGPR_Count=28 / SGPR=80 — the ~55-reg live set was demoted/remat'd
//      and the 90 SGPR-pinned weights couldn't fit (spill pathology).
// Layout (verified correct in R5): lane = item*32 + h*16 + q*8 + x;
// register r holds row y = h*4 + 2r + q. Vertical taps = row_shr:8/
// row_shl:8 DPP sums (exactly one term nonzero); the y=3<->4 crossing is
// one static ds_swizzle (lane^24) per source reg: 2 DS ops per scan step.
// ---------------------------------------------------------------------------
__global__ __launch_bounds__(256, 6) void vin_kernel(
    const float* __restrict__ S,
    const float* __restrict__ Wq,
    const float* __restrict__ w,
    const float* __restrict__ Wfc,
    const float* __restrict__ ws,
    float* __restrict__ out,
    int B) {
    const int wave = threadIdx.x >> 6;
    const int lane = threadIdx.x & 63;
    const long b0 = (long)(blockIdx.x * 4 + wave) * 2;   // items b0, b0+1
    if (b0 >= B) return;                                  // wave-uniform

    const int item = lane >> 5;        // 0,1
    const int l32  = lane & 31;
    const int h    = l32 >> 4;         // y half (0: y=0..3, 1: y=4..7)
    const int q    = (l32 >> 3) & 1;   // row parity within half
    const int x    = l32 & 7;

    const float mskL = (x > 0) ? 1.f : 0.f;
    const float mskR = (x < 7) ? 1.f : 0.f;
    const float m3   = (h == 1 && q == 0) ? 1.f : 0.f;  // consumers of y=3 via swz
    const float m4   = (h == 0 && q == 1) ? 1.f : 0.f;  // consumers of y=4 via swz

    // ---- per-item state
    const long b = b0 + item;
    const float* Sb = S + b * ROW;
    float v[2];
    v[0] = Sb[(h * 4 + q) * 8 + x];        // y = h4 + q     (r=0)
    v[1] = Sb[(h * 4 + 2 + q) * 8 + x];    // y = h4 + 2 + q (r=1)
    const int s1i = (int)Sb[IMG * IMG];
    const int s2i = (int)Sb[IMG * IMG + 1];
    // lane holding (s1,s2): y=s1 -> h=s1>>2, q=s1&1, reg r=(s1>>1)&1
    const int selAddr = ((item << 5) + ((s1i >> 2) << 4) + ((s1i & 1) << 3) + s2i) << 2;
    const float e0 = (((s1i >> 1) & 1) == 0) ? 1.f : 0.f;
    const float e1 = 1.f - e0;

    // Build the 5 window rows d[j] = grid row (h4+q + j-1), j=0..4, and the
    // x-shifted copies. Output r uses rows d[2r..2r+2].
    auto rows5 = [&](const float vv[2], float d[5]) {
        const float X3 = swz24(vv[1]);   // y=3 -> lanes (h1,q0)
        const float X4 = swz24(vv[0]);   // y=4 -> lanes (h0,q1)
        d[1] = vv[0];
        d[3] = vv[1];
        d[2] = dppf<DPP_SHL8>(vv[0]) + dppf<DPP_SHR8>(vv[1]);
        d[0] = fmaf(X3, m3, dppf<DPP_SHR8>(vv[0]));
        d[4] = fmaf(X4, m4, dppf<DPP_SHL8>(vv[1]));
    };
    auto lcr = [&](const float d[5], float L[5], float R[5]) {
        #pragma unroll
        for (int j = 0; j < 5; ++j) {
            L[j] = mskL * dppf<DPP_SHR1>(d[j]);
            R[j] = mskR * dppf<DPP_SHL1>(d[j]);
        }
    };

    // --- r = conv(X, Weff, pad=1) + beff  (in place: v becomes r)
    {
        float d[5], L[5], R[5];
        rows5(v, d); lcr(d, L, R);
        const float bias = ws[9];
        #pragma unroll
        for (int r = 0; r < 2; ++r) {
            float a = bias;
            #pragma unroll
            for (int ky = 0; ky < 3; ++ky) {
                const int j = 2 * r + ky;
                a = fmaf(L[j], ws[ky * 3 + 0], a);
                a = fmaf(d[j], ws[ky * 3 + 1], a);
                a = fmaf(R[j], ws[ky * 3 + 2], a);
            }
            v[r] = a;   // d/L/R already captured old v
        }
    }

    // --- qr[o] = conv(r, Wq, pad=1) — loop-invariant across the scan.
    float qr[LQ][2];
    {
        float d[5], L[5], R[5];
        rows5(v, d); lcr(d, L, R);
        #pragma unroll
        for (int o = 0; o < LQ; ++o)
            #pragma unroll
            for (int r = 0; r < 2; ++r) {
                float a = L[2 * r] * Wq[o * 9 + 0];
                a = fmaf(d[2 * r],     Wq[o * 9 + 1], a);
                a = fmaf(R[2 * r],     Wq[o * 9 + 2], a);
                a = fmaf(L[2 * r + 1], Wq[o * 9 + 3], a);
                a = fmaf(d[2 * r + 1], Wq[o * 9 + 4], a);
                a = fmaf(R[2 * r + 1], Wq[o * 9 + 5], a);
                a = fmaf(L[2 * r + 2], Wq[o * 9 + 6], a);
                a = fmaf(d[2 * r + 2], Wq[o * 9 + 7], a);
                a = fmaf(R[2 * r + 2], Wq[o * 9 + 8], a);
                qr[o][r] = a;
            }
    }

    // Pin the 90 scan weights to SGPRs (one-time; scan body then has only
    // 2 ds_swizzle + VALU).
    float wu[LQ][9];
    #pragma unroll
    for (int o = 0; o < LQ; ++o)
        #pragma unroll
        for (int t = 0; t < 9; ++t)
            wu[o][t] = rfl(w[o * 9 + t]);

    // v = max over channels of qr (same tree shape as verified max10)
    #pragma unroll
    for (int r = 0; r < 2; ++r) {
        const float g0 = fmaxf(fmaxf(qr[0][r], qr[1][r]), qr[2][r]);
        const float g1 = fmaxf(fmaxf(qr[3][r], qr[4][r]), qr[5][r]);
        const float g2 = fmaxf(fmaxf(qr[6][r], qr[7][r]), qr[8][r]);
        v[r] = fmaxf(fmaxf(g0, g1), fmaxf(g2, qr[9][r]));
    }

    // --- 9 scan steps: 2 ds_swizzle + DPP taps + 180 fma + max.
    #pragma unroll 3
    for (int k = 0; k < KITER - 1; ++k) {
        float d[5], L[5], R[5];
        rows5(v, d); lcr(d, L, R);
        float m[2];
        #pragma unroll
        for (int o = 0; o < LQ; ++o)
            #pragma unroll
            for (int r = 0; r < 2; ++r) {
                float a = qr[o][r];
                a = fmaf(L[2 * r],     wu[o][0], a);
                a = fmaf(d[2 * r],     wu[o][1], a);
                a = fmaf(R[2 * r],     wu[o][2], a);
                a = fmaf(L[2 * r + 1], wu[o][3], a);
                a = fmaf(d[2 * r + 1], wu[o][4], a);
                a = fmaf(R[2 * r + 1], wu[o][5], a);
                a = fmaf(L[2 * r + 2], wu[o][6], a);
                a = fmaf(d[2 * r + 2], wu[o][7], a);
                a = fmaf(R[2 * r + 2], wu[o][8], a);
                m[r] = (o == 0) ? a : fmaxf(m[r], a);
            }
        v[0] = m[0]; v[1] = m[1];
    }

    // --- Final conv fused with sel extraction + Wfc dot.
    const int row = l32 & 7;
    float osum = 0.f;
    {
        float d[5], L[5], R[5];
        rows5(v, d); lcr(d, L, R);
        #pragma unroll
        for (int o = 0; o < LQ; ++o) {
            float a0, a1;
            #pragma unroll
            for (int r = 0; r < 2; ++r) {
                float a = qr[o][r];
                a = fmaf(L[2 * r],     wu[o][0], a);
                a = fmaf(d[2 * r],     wu[o][1], a);
                a = fmaf(R[2 * r],     wu[o][2], a);
                a = fmaf(L[2 * r + 1], wu[o][3], a);
                a = fmaf(d[2 * r + 1], wu[o][4], a);
                a = fmaf(R[2 * r + 1], wu[o][5], a);
                a = fmaf(L[2 * r + 2], wu[o][6], a);
                a = fmaf(d[2 * r + 2], wu[o][7], a);
                a = fmaf(R[2 * r + 2], wu[o][8], a);
                if (r == 0) a0 = a; else a1 = a;
            }
            float t = a0 * e0;
            t = fmaf(a1, e1, t);                  // one-hot reg select (exact)
            const float qs = bperm(selAddr, t);   // full convergence
            osum = fmaf(qs, Wfc[row * LQ + o], osum);
        }
    }
    // lanes 0..7 of each 32-lane item group emit that item's 8 logits
    if (l32 < 8) out[b * 8 + row] = osum;
}

extern "C" void kernel_launch(void* const* d_in, const int* in_sizes, int n_in,
                              void* d_out, int out_size, void* d_ws, size_t ws_size,
                              hipStream_t stream) {
    const float* S   = (const float*)d_in[0];
    const float* Wh  = (const float*)d_in[1];
    const float* bh  = (const float*)d_in[2];
    const float* Wr  = (const float*)d_in[3];
    const float* Wq  = (const float*)d_in[4];
    const float* w   = (const float*)d_in[5];
    const float* Wfc = (const float*)d_in[6];
    float* out = (float*)d_out;
    float* ws  = (float*)d_ws;

    const int B = in_sizes[0] / ROW;

    weff_kernel<<<1, 640, 0, stream>>>(Wh, bh, Wr, ws);

    // 4 waves/block, 2 items/wave => 8 items per block.
    const int grid = (B + 7) / 8;
    vin_kernel<<<grid, 256, 0, stream>>>(S, Wq, w, Wfc, ws, out, B);
}